// Round 7
// baseline (136.501 us; speedup 1.0000x reference)
//
#include <hip/hip_runtime.h>

#define DEV __device__ __forceinline__

// Hardware waits + compiler reorder fences.
#define LDS_FENCE() asm volatile("s_waitcnt lgkmcnt(0)" ::: "memory")
#define VM_FENCE()  asm volatile("s_waitcnt vmcnt(0)" ::: "memory")

typedef float f32x2 __attribute__((ext_vector_type(2)));

// Direct global->LDS DMA, 16B per lane. LDS dest = uniform base + lane*16,
// global src = per-lane address.
DEV void gload_lds16(const void* g, void* lds) {
    __builtin_amdgcn_global_load_lds(
        (const __attribute__((address_space(1))) void*)g,
        (__attribute__((address_space(3))) void*)lds,
        16, 0, 0);
}

// Packed fp32 FMA: acc.{x,y} += ab.{x,y} * w.{x,y}. The "s" constraint forces
// the (wave-uniform) weight pair into SGPRs -> s_load path, no VALU/LDS cost.
DEV void pk_fma_sw(f32x2& acc, f32x2 ab, f32x2 w) {
    asm("v_pk_fma_f32 %0, %1, %2, %0" : "+v"(acc) : "v"(ab), "s"(w));
}

DEV float fast_sigmoid(float v) {
    return __builtin_amdgcn_rcpf(1.0f + __builtin_amdgcn_exp2f(-1.4426950408889634f * v));
}

// Per-sample math; weights read uniformly from global (scalar cache).
DEV void compute_sample(const float (&p)[51], const float (&a)[17], const float (&g)[16],
                        const float* __restrict__ gW1, const float* __restrict__ gW2,
                        float (&o)[51])
{
    constexpr int PAR[16] = {0,1,2,0,4,5,0,7,8,9,8,11,12,8,14,15};
    constexpr int CHI[16] = {1,2,3,4,5,6,7,8,9,10,11,12,13,14,15,16};

    float x[32], invn[16];
    #pragma unroll
    for (int k = 0; k < 16; ++k) {
        const int P = PAR[k] * 3, C = CHI[k] * 3;
        const float dx = p[P]   - p[C];
        const float dy = p[P+1] - p[C+1];
        const float dz = p[P+2] - p[C+2];
        const float n  = __builtin_amdgcn_sqrtf(fmaf(dx,dx, fmaf(dy,dy, dz*dz)));
        const float dis = g[k] - n;
        const float ap = a[PAR[k]], ac = a[CHI[k]];
        const float inv_asum = __builtin_amdgcn_rcpf(ap + ac + 1e-9f);
        x[2*k]   = dis * ac * inv_asum;
        x[2*k+1] = dis * ap * inv_asum;
        invn[k]  = __builtin_amdgcn_rcpf(n + 1e-9f);
    }

    const f32x2* W1p = reinterpret_cast<const f32x2*>(gW1);  // [32][8] pairs
    const f32x2* W2p = reinterpret_cast<const f32x2*>(gW2);  // [16][16] pairs

    // ---- layer 1: y[16] = relu(x @ W1), output-paired packed FMA ----
    f32x2 acc1[8];
    #pragma unroll
    for (int jj = 0; jj < 8; ++jj) acc1[jj] = (f32x2){0.f, 0.f};
    #pragma unroll
    for (int i = 0; i < 32; ++i) {
        const f32x2 xx = {x[i], x[i]};
        #pragma unroll
        for (int jj = 0; jj < 8; ++jj)
            pk_fma_sw(acc1[jj], xx, W1p[i*8 + jj]);
    }
    float h[16];
    #pragma unroll
    for (int jj = 0; jj < 8; ++jj) {
        h[2*jj]   = fmaxf(acc1[jj].x, 0.f);
        h[2*jj+1] = fmaxf(acc1[jj].y, 0.f);
    }

    // ---- layer 2: gate = sigmoid(h @ W2), output-paired packed FMA ----
    f32x2 acc2[16];
    #pragma unroll
    for (int cc = 0; cc < 16; ++cc) acc2[cc] = (f32x2){0.f, 0.f};
    #pragma unroll
    for (int j = 0; j < 16; ++j) {
        const f32x2 hh = {h[j], h[j]};
        #pragma unroll
        for (int cc = 0; cc < 16; ++cc)
            pk_fma_sw(acc2[cc], hh, W2p[j*16 + cc]);
    }

    float xg[32];
    #pragma unroll
    for (int cc = 0; cc < 16; ++cc) {
        xg[2*cc]   = x[2*cc]   * fast_sigmoid(acc2[cc].x);
        xg[2*cc+1] = x[2*cc+1] * fast_sigmoid(acc2[cc].y);
    }
    #pragma unroll
    for (int k = 0; k < 16; ++k) {
        xg[2*k]   *= invn[k];
        xg[2*k+1] *= invn[k];
    }

    #pragma unroll
    for (int j = 0; j < 17; ++j) {
        float ox = p[3*j], oy = p[3*j+1], oz = p[3*j+2];
        #pragma unroll
        for (int k = 0; k < 16; ++k) {
            if (PAR[k] == j || CHI[k] == j) {   // compile-time after unroll
                const int P = PAR[k] * 3, C = CHI[k] * 3;
                const float dx = p[P]   - p[C];
                const float dy = p[P+1] - p[C+1];
                const float dz = p[P+2] - p[C+2];
                const float s = (PAR[k] == j) ? xg[2*k] : -xg[2*k+1];
                ox = fmaf(s, dx, ox);
                oy = fmaf(s, dy, oy);
                oz = fmaf(s, dz, oz);
            }
        }
        o[3*j]   = ox;
        o[3*j+1] = oy;
        o[3*j+2] = oz;
    }
}

__global__ __launch_bounds__(256, 2) void projts_kernel(
    const float* __restrict__ pred,
    const float* __restrict__ gt,
    const float* __restrict__ anc,
    const float* __restrict__ gW1,
    const float* __restrict__ gW2,
    float* __restrict__ out,
    int B)
{
    constexpr int ROW = 51;            // floats per sample in pred/out
    constexpr int WBUF = 64 * ROW;     // 3264 dwords = 13056 B per wave
    constexpr int ABUF = 64 * 17;      // 1088 dwords = 4352 B per wave

    __shared__ float sbuf[4][WBUF] __attribute__((aligned(16)));  // pred/out
    __shared__ float abuf[4][ABUF] __attribute__((aligned(16)));  // anchors

    const int t = threadIdx.x;
    const int w = t >> 6;
    const int l = t & 63;
    const long long wavebase = ((long long)blockIdx.x * 4 + w) * 64;
    if (wavebase >= B) return;

    float* buf  = sbuf[w];
    float4* buf4 = reinterpret_cast<float4*>(buf);
    float* abf  = abuf[w];

    if (wavebase + 64 <= (long long)B) {
        // ================= coalesced fast path (full wave) =================
        float p[51], a[17], o[51];

        const char* srcB = reinterpret_cast<const char*>(pred + (size_t)wavebase * ROW);
        const char* ascB = reinterpret_cast<const char*>(anc + (size_t)wavebase * 17);
        char* bufB = reinterpret_cast<char*>(buf);
        char* abfB = reinterpret_cast<char*>(abf);

        // ---- pred: 816 float4 via global_load_lds (13 issues, last masked) ----
        #pragma unroll
        for (int i = 0; i < 12; ++i)
            gload_lds16(srcB + (size_t)(i*64 + l)*16, bufB + i*1024);
        if (l < 48)
            gload_lds16(srcB + (size_t)(768 + l)*16, bufB + 12*1024);

        // ---- anchors: 272 float4 via global_load_lds (5 issues, last masked) ----
        #pragma unroll
        for (int i = 0; i < 4; ++i)
            gload_lds16(ascB + (size_t)(i*64 + l)*16, abfB + i*1024);
        if (l < 16)
            gload_lds16(ascB + (size_t)(256 + l)*16, abfB + 4*1024);

        // ---- gt: 64B/sample, 16B aligned -> direct float4 reg loads ----
        const float4* gsrc4 = reinterpret_cast<const float4*>(gt + (size_t)(wavebase + l) * 16);
        const float4 gq0 = gsrc4[0], gq1 = gsrc4[1], gq2 = gsrc4[2], gq3 = gsrc4[3];

        VM_FENCE();    // all global_load_lds (and gt loads) complete

        // ---- transposed readback: strides 51 / 17 (odd) -> conflict-free ----
        #pragma unroll
        for (int j = 0; j < ROW; ++j) p[j] = buf[l*ROW + j];
        #pragma unroll
        for (int j = 0; j < 17; ++j) a[j] = abf[l*17 + j];
        LDS_FENCE();   // reads drained before out overwrites pred region (WAR)

        const float g[16] = {gq0.x,gq0.y,gq0.z,gq0.w, gq1.x,gq1.y,gq1.z,gq1.w,
                             gq2.x,gq2.y,gq2.z,gq2.w, gq3.x,gq3.y,gq3.z,gq3.w};

        compute_sample(p, a, g, gW1, gW2, o);

        // ---- transpose out through LDS (reuse pred region), coalesced stores ----
        #pragma unroll
        for (int j = 0; j < ROW; ++j) buf[l*ROW + j] = o[j];
        LDS_FENCE();

        float4* dst4 = reinterpret_cast<float4*>(out + (size_t)wavebase * ROW);
        #pragma unroll
        for (int i = 0; i < 12; ++i) dst4[i*64 + l] = buf4[i*64 + l];
        if (l < 48) dst4[768 + l] = buf4[768 + l];
    } else {
        // ================= scalar tail path (partial wave) =================
        const long long b = wavebase + l;
        if (b < B) {
            float p[51], a[17], g[16], o[51];
            const float* pj = pred + (size_t)b * 51;
            #pragma unroll
            for (int j = 0; j < 51; ++j) p[j] = pj[j];
            const float* ab = anc + (size_t)b * 17;
            #pragma unroll
            for (int j = 0; j < 17; ++j) a[j] = ab[j];
            const float* gb = gt + (size_t)b * 16;
            #pragma unroll
            for (int j = 0; j < 16; ++j) g[j] = gb[j];

            compute_sample(p, a, g, gW1, gW2, o);

            float* ob = out + (size_t)b * 51;
            #pragma unroll
            for (int j = 0; j < 51; ++j) ob[j] = o[j];
        }
    }
}

extern "C" void kernel_launch(void* const* d_in, const int* in_sizes, int n_in,
                              void* d_out, int out_size, void* d_ws, size_t ws_size,
                              hipStream_t stream) {
    const float* pred = (const float*)d_in[0];
    const float* gt   = (const float*)d_in[1];
    const float* anc  = (const float*)d_in[2];
    const float* W1   = (const float*)d_in[3];
    const float* W2   = (const float*)d_in[4];
    float* out = (float*)d_out;

    const int B = in_sizes[0] / 51;
    const int blocks = (B + 255) / 256;
    hipLaunchKernelGGL(projts_kernel, dim3(blocks), dim3(256), 0, stream,
                       pred, gt, anc, W1, W2, out, B);
}

// Round 10
// 109.510 us; speedup vs baseline: 1.2465x; 1.2465x over previous
//
#include <hip/hip_runtime.h>

#define DEV __device__ __forceinline__

// Hardware waits + compiler reorder fences.
#define LDS_FENCE() asm volatile("s_waitcnt lgkmcnt(0)" ::: "memory")
#define VM_FENCE()  asm volatile("s_waitcnt vmcnt(0)" ::: "memory")

typedef __fp16 h16x2 __attribute__((ext_vector_type(2)));

// Direct global->LDS DMA, 16B per lane. LDS dest = uniform base + lane*16,
// global src = per-lane address.
DEV void gload_lds16(const void* g, void* lds) {
    __builtin_amdgcn_global_load_lds(
        (const __attribute__((address_space(1))) void*)g,
        (__attribute__((address_space(3))) void*)lds,
        16, 0, 0);
}

// v_dot2_f32_f16: acc += a.x*b.x + a.y*b.y (fp16 mul, fp32 accumulate)
DEV float dot2(h16x2 a, h16x2 b, float acc) {
    asm("v_dot2_f32_f16 %0, %1, %2, %0" : "+v"(acc) : "v"(a), "v"(b));
    return acc;
}

DEV h16x2 f2h(float a, float b) { return __builtin_amdgcn_cvt_pkrtz(a, b); }

DEV float fast_sigmoid(float v) {
    return __builtin_amdgcn_rcpf(1.0f + __builtin_amdgcn_exp2f(-1.4426950408889634f * v));
}

// Per-sample math. Weights: k-pair-packed half2 in LDS (broadcast reads).
// sW1h: [16 i-pairs][16 j]  half2 ; sW2h: [8 j-pairs][32 c] half2.
DEV void compute_sample(const float (&p)[51], const float (&a)[17], const float (&g)[16],
                        const float4* sW1h4, const float4* sW2h4, float (&o)[51])
{
    constexpr int PAR[16] = {0,1,2,0,4,5,0,7,8,9,8,11,12,8,14,15};
    constexpr int CHI[16] = {1,2,3,4,5,6,7,8,9,10,11,12,13,14,15,16};

    float x[32], invn[16];
    #pragma unroll
    for (int k = 0; k < 16; ++k) {
        const int P = PAR[k] * 3, C = CHI[k] * 3;
        const float dx = p[P]   - p[C];
        const float dy = p[P+1] - p[C+1];
        const float dz = p[P+2] - p[C+2];
        const float n  = __builtin_amdgcn_sqrtf(fmaf(dx,dx, fmaf(dy,dy, dz*dz)));
        const float dis = g[k] - n;
        const float ap = a[PAR[k]], ac = a[CHI[k]];
        const float inv_asum = __builtin_amdgcn_rcpf(ap + ac + 1e-9f);
        x[2*k]   = dis * ac * inv_asum;
        x[2*k+1] = dis * ap * inv_asum;
        invn[k]  = __builtin_amdgcn_rcpf(n + 1e-9f);
    }

    // ---- pack x into k-pairs (half2) ----
    h16x2 xp[16];
    #pragma unroll
    for (int ip = 0; ip < 16; ++ip) xp[ip] = f2h(x[2*ip], x[2*ip+1]);

    // ---- layer 1: y[16] = relu(x @ W1), dot2 over k-pairs ----
    float y[16];
    #pragma unroll
    for (int j = 0; j < 16; ++j) y[j] = 0.f;
    #pragma unroll
    for (int ip = 0; ip < 16; ++ip) {
        #pragma unroll
        for (int jj = 0; jj < 4; ++jj) {
            const float4 wq = sW1h4[ip*4 + jj];      // 4 half2: j = 4jj..4jj+3
            y[4*jj+0] = dot2(xp[ip], __builtin_bit_cast(h16x2, wq.x), y[4*jj+0]);
            y[4*jj+1] = dot2(xp[ip], __builtin_bit_cast(h16x2, wq.y), y[4*jj+1]);
            y[4*jj+2] = dot2(xp[ip], __builtin_bit_cast(h16x2, wq.z), y[4*jj+2]);
            y[4*jj+3] = dot2(xp[ip], __builtin_bit_cast(h16x2, wq.w), y[4*jj+3]);
        }
    }
    h16x2 hp[8];
    #pragma unroll
    for (int jp = 0; jp < 8; ++jp)
        hp[jp] = f2h(fmaxf(y[2*jp], 0.f), fmaxf(y[2*jp+1], 0.f));

    // ---- layer 2: gate[32] = h @ W2, dot2 over j-pairs ----
    float gg[32];
    #pragma unroll
    for (int c = 0; c < 32; ++c) gg[c] = 0.f;
    #pragma unroll
    for (int jp = 0; jp < 8; ++jp) {
        #pragma unroll
        for (int cc = 0; cc < 8; ++cc) {
            const float4 wq = sW2h4[jp*8 + cc];      // 4 half2: c = 4cc..4cc+3
            gg[4*cc+0] = dot2(hp[jp], __builtin_bit_cast(h16x2, wq.x), gg[4*cc+0]);
            gg[4*cc+1] = dot2(hp[jp], __builtin_bit_cast(h16x2, wq.y), gg[4*cc+1]);
            gg[4*cc+2] = dot2(hp[jp], __builtin_bit_cast(h16x2, wq.z), gg[4*cc+2]);
            gg[4*cc+3] = dot2(hp[jp], __builtin_bit_cast(h16x2, wq.w), gg[4*cc+3]);
        }
    }

    float xg[32];
    #pragma unroll
    for (int c = 0; c < 32; ++c) xg[c] = x[c] * fast_sigmoid(gg[c]);
    #pragma unroll
    for (int k = 0; k < 16; ++k) {
        xg[2*k]   *= invn[k];
        xg[2*k+1] *= invn[k];
    }

    #pragma unroll
    for (int j = 0; j < 17; ++j) {
        float ox = p[3*j], oy = p[3*j+1], oz = p[3*j+2];
        #pragma unroll
        for (int k = 0; k < 16; ++k) {
            if (PAR[k] == j || CHI[k] == j) {   // compile-time after unroll
                const int P = PAR[k] * 3, C = CHI[k] * 3;
                const float dx = p[P]   - p[C];
                const float dy = p[P+1] - p[C+1];
                const float dz = p[P+2] - p[C+2];
                const float s = (PAR[k] == j) ? xg[2*k] : -xg[2*k+1];
                ox = fmaf(s, dx, ox);
                oy = fmaf(s, dy, oy);
                oz = fmaf(s, dz, oz);
            }
        }
        o[3*j]   = ox;
        o[3*j+1] = oy;
        o[3*j+2] = oz;
    }
}

__global__ __launch_bounds__(256, 2) void projts_kernel(
    const float* __restrict__ pred,
    const float* __restrict__ gt,
    const float* __restrict__ anc,
    const float* __restrict__ gW1,
    const float* __restrict__ gW2,
    float* __restrict__ out,
    int B)
{
    constexpr int ROW = 51;            // floats per sample in pred/out
    constexpr int WBUF = 64 * ROW;     // 3264 dwords = 13056 B per wave
    constexpr int ABUF = 64 * 17;      // 1088 dwords = 4352 B per wave

    __shared__ h16x2 sW1h[256] __attribute__((aligned(16)));  // [16 ipair][16 j]
    __shared__ h16x2 sW2h[256] __attribute__((aligned(16)));  // [8 jpair][32 c]
    __shared__ float sbuf[4][WBUF] __attribute__((aligned(16)));  // pred/out
    __shared__ float abuf[4][ABUF] __attribute__((aligned(16)));  // anchors

    const int t = threadIdx.x;

    // ---- one-time weight convert fp32 -> packed half2 (2 KB LDS) ----
    {
        // layer1 entry t: ip = t>>4, j = t&15 ; pairs W1[2ip][j], W1[2ip+1][j]
        const int ip = t >> 4, j = t & 15;
        sW1h[t] = f2h(gW1[32*ip + j], gW1[32*ip + 16 + j]);
        // layer2 entry t: jp = t>>5, c = t&31 ; pairs W2[2jp][c], W2[2jp+1][c]
        const int jp = t >> 5, c = t & 31;
        sW2h[t] = f2h(gW2[64*jp + c], gW2[64*jp + 32 + c]);
    }
    __syncthreads();

    const float4* sW1h4 = reinterpret_cast<const float4*>(sW1h);
    const float4* sW2h4 = reinterpret_cast<const float4*>(sW2h);

    const int w = t >> 6;
    const int l = t & 63;
    const long long wavebase = ((long long)blockIdx.x * 4 + w) * 64;
    if (wavebase >= B) return;

    float* buf  = sbuf[w];
    float4* buf4 = reinterpret_cast<float4*>(buf);
    float* abf  = abuf[w];

    if (wavebase + 64 <= (long long)B) {
        // ================= coalesced fast path (full wave) =================
        float p[51], a[17], o[51];

        const char* srcB = reinterpret_cast<const char*>(pred + (size_t)wavebase * ROW);
        const char* ascB = reinterpret_cast<const char*>(anc + (size_t)wavebase * 17);
        char* bufB = reinterpret_cast<char*>(buf);
        char* abfB = reinterpret_cast<char*>(abf);

        // ---- pred: 816 float4 via global_load_lds (13 issues, last masked) ----
        #pragma unroll
        for (int i = 0; i < 12; ++i)
            gload_lds16(srcB + (size_t)(i*64 + l)*16, bufB + i*1024);
        if (l < 48)
            gload_lds16(srcB + (size_t)(768 + l)*16, bufB + 12*1024);

        // ---- anchors: 272 float4 via global_load_lds (5 issues, last masked) ----
        #pragma unroll
        for (int i = 0; i < 4; ++i)
            gload_lds16(ascB + (size_t)(i*64 + l)*16, abfB + i*1024);
        if (l < 16)
            gload_lds16(ascB + (size_t)(256 + l)*16, abfB + 4*1024);

        // ---- gt: 64B/sample, 16B aligned -> direct float4 reg loads ----
        const float4* gsrc4 = reinterpret_cast<const float4*>(gt + (size_t)(wavebase + l) * 16);
        const float4 gq0 = gsrc4[0], gq1 = gsrc4[1], gq2 = gsrc4[2], gq3 = gsrc4[3];

        VM_FENCE();    // all global_load_lds (and gt loads) complete

        // ---- transposed readback: strides 51 / 17 (odd) -> conflict-free ----
        #pragma unroll
        for (int j = 0; j < ROW; ++j) p[j] = buf[l*ROW + j];
        #pragma unroll
        for (int j = 0; j < 17; ++j) a[j] = abf[l*17 + j];
        LDS_FENCE();   // reads drained before out overwrites pred region (WAR)

        const float g[16] = {gq0.x,gq0.y,gq0.z,gq0.w, gq1.x,gq1.y,gq1.z,gq1.w,
                             gq2.x,gq2.y,gq2.z,gq2.w, gq3.x,gq3.y,gq3.z,gq3.w};

        compute_sample(p, a, g, sW1h4, sW2h4, o);

        // ---- transpose out through LDS (reuse pred region), coalesced stores ----
        #pragma unroll
        for (int j = 0; j < ROW; ++j) buf[l*ROW + j] = o[j];
        LDS_FENCE();

        float4* dst4 = reinterpret_cast<float4*>(out + (size_t)wavebase * ROW);
        #pragma unroll
        for (int i = 0; i < 12; ++i) dst4[i*64 + l] = buf4[i*64 + l];
        if (l < 48) dst4[768 + l] = buf4[768 + l];
    } else {
        // ================= scalar tail path (partial wave) =================
        const long long b = wavebase + l;
        if (b < B) {
            float p[51], a[17], g[16], o[51];
            const float* pj = pred + (size_t)b * 51;
            #pragma unroll
            for (int j = 0; j < 51; ++j) p[j] = pj[j];
            const float* ab = anc + (size_t)b * 17;
            #pragma unroll
            for (int j = 0; j < 17; ++j) a[j] = ab[j];
            const float* gb = gt + (size_t)b * 16;
            #pragma unroll
            for (int j = 0; j < 16; ++j) g[j] = gb[j];

            compute_sample(p, a, g, sW1h4, sW2h4, o);

            float* ob = out + (size_t)b * 51;
            #pragma unroll
            for (int j = 0; j < 51; ++j) ob[j] = o[j];
        }
    }
}

extern "C" void kernel_launch(void* const* d_in, const int* in_sizes, int n_in,
                              void* d_out, int out_size, void* d_ws, size_t ws_size,
                              hipStream_t stream) {
    const float* pred = (const float*)d_in[0];
    const float* gt   = (const float*)d_in[1];
    const float* anc  = (const float*)d_in[2];
    const float* W1   = (const float*)d_in[3];
    const float* W2   = (const float*)d_in[4];
    float* out = (float*)d_out;

    const int B = in_sizes[0] / 51;
    const int blocks = (B + 255) / 256;
    hipLaunchKernelGGL(projts_kernel, dim3(blocks), dim3(256), 0, stream,
                       pred, gt, anc, W1, W2, out, B);
}